// Round 3
// baseline (1874.165 us; speedup 1.0000x reference)
//
#include <hip/hip_runtime.h>
#include <math.h>

#define B_     128
#define L_     100
#define HID_   256
#define IND_   160
#define NCLASS 19
#define CAPD   16
#define NI     1600      // L_ * NUM_CAPS
#define OD     304       // NCLASS * CAPD
#define ENTITY 68

// ---------------------------------------------------------------------------
// Phase 0: embedding gather -> emb [b*L_+t][160]
// ---------------------------------------------------------------------------
__global__ void emb_gather(const int* __restrict__ word, const int* __restrict__ tag,
                           const int* __restrict__ pos1, const int* __restrict__ pos2,
                           const float* __restrict__ we, const float* __restrict__ te,
                           const float* __restrict__ p1e, const float* __restrict__ p2e,
                           float* __restrict__ emb)
{
    int idx = blockIdx.x * 256 + threadIdx.x;          // exactly B_*L_*IND_ threads
    int bt = idx / IND_;
    int k  = idx - bt * IND_;
    float v;
    if (k < 100)      v = we[word[bt] * 100 + k];
    else if (k < 120) v = te[tag[bt] * 20 + (k - 100)];
    else if (k < 140) v = p1e[pos1[bt] * 20 + (k - 120)];
    else              v = p2e[pos2[bt] * 20 + (k - 140)];
    emb[idx] = v;
}

// ---------------------------------------------------------------------------
// Phase 1: input-gate GEMM.
// xg layout: [dir][t][bpair(64)][gj(1024)][2]  (b = bpair*2 + c)
// so the scan's per-step gate load is a coalesced dwordx2 over lanes=hid.
// ---------------------------------------------------------------------------
__global__ void __launch_bounds__(256) gemm_xg(
    const float* __restrict__ emb,
    const float* __restrict__ wihf, const float* __restrict__ bihf, const float* __restrict__ bhhf,
    const float* __restrict__ wihb, const float* __restrict__ bihb, const float* __restrict__ bhhb,
    float* __restrict__ xg)
{
    int gt  = blockIdx.x;
    int t   = blockIdx.y;
    int dir = blockIdx.z;
    const float* w  = dir ? wihb : wihf;
    const float* bi = dir ? bihb : bihf;
    const float* bh = dir ? bhhb : bhhf;
    int gj0 = gt * 128;

    __shared__ float wsh[32][132];   // [k][gj], padded
    __shared__ float esh[32][132];   // [k][b],  padded

    int tid = threadIdx.x;
    int tx = tid & 15, ty = tid >> 4;

    float acc[8][8];
    #pragma unroll
    for (int i = 0; i < 8; ++i)
        #pragma unroll
        for (int j = 0; j < 8; ++j) acc[i][j] = 0.f;

    for (int k0 = 0; k0 < IND_; k0 += 32) {
        __syncthreads();
        #pragma unroll
        for (int m = 0; m < 16; ++m) {
            int e = m * 256 + tid;        // 0..4095
            int k = e & 31, g = e >> 5;   // g: row (gj or b)
            wsh[k][g] = w[(gj0 + g) * IND_ + k0 + k];
            esh[k][g] = emb[(g * L_ + t) * IND_ + k0 + k];
        }
        __syncthreads();
        #pragma unroll
        for (int k = 0; k < 32; ++k) {
            float wv[8], ev[8];
            #pragma unroll
            for (int q = 0; q < 8; ++q) wv[q] = wsh[k][ty * 8 + q];
            #pragma unroll
            for (int q = 0; q < 8; ++q) ev[q] = esh[k][tx * 8 + q];
            #pragma unroll
            for (int i = 0; i < 8; ++i)
                #pragma unroll
                for (int j = 0; j < 8; ++j) acc[i][j] = fmaf(wv[i], ev[j], acc[i][j]);
        }
    }
    #pragma unroll
    for (int i = 0; i < 8; ++i) {
        int gj = gj0 + ty * 8 + i;
        float bias = bi[gj] + bh[gj];
        #pragma unroll
        for (int j = 0; j < 8; ++j) {
            int b = tx * 8 + j;
            xg[((((size_t)dir * L_ + t) * 64 + (b >> 1)) * 1024 + gj) * 2 + (b & 1)]
                = acc[i][j] + bias;
        }
    }
}

// ---------------------------------------------------------------------------
// Phase 1.5: transpose-pack recurrent weights.
// wtp[dir][gate][k4][hid] = float4{whh[gate*256+hid][4k4+0..3]}, hid fastest.
// In the scan a wave's 64 lanes (consecutive hid) load 64 consecutive float4
// per (gate,k4) -> fully-contiguous 1KB, full L2-line utilization.
// ---------------------------------------------------------------------------
__global__ void whh_pack(const float* __restrict__ whhf, const float* __restrict__ whhb,
                         float4* __restrict__ wtp)
{
    int gid = blockIdx.x * 256 + threadIdx.x;   // exactly 2*4*64*256 threads
    int dir  = gid >> 16;
    int rem  = gid & 65535;
    int gate = rem >> 14;
    int k4   = (rem >> 8) & 63;
    int hid  = rem & 255;
    const float* whh = dir ? whhb : whhf;
    float4 v = *(const float4*)(whh + ((size_t)(gate * 256 + hid)) * HID_ + k4 * 4);
    wtp[gid] = v;                               // one-time 2MB scatter-pack
}

// ---------------------------------------------------------------------------
// Phase 2: BiLSTM scan. Block = (dir, b-pair): 128 blocks x 256 threads.
// Thread = one hidden unit: computes ALL 4 gate dot-products for 2 batch
// columns (2048 FMA/step) from ONE pass over h (128 ds_read_b128/step).
// This 4x-amortizes the LDS pipe (was the binding pipe at 16 waves x 128
// reads = ~10us/step). Gate coupling is now thread-local: no gs exchange,
// double-buffered hs -> 1 barrier/step. 4 waves/block (1/SIMD): deep unroll
// + 512-VGPR headroom pipelines the L2 weight stream.
// Floors: L2 3.7us, LDS 2.6us, VALU 1.7us per step.
// ---------------------------------------------------------------------------
__global__ void __launch_bounds__(256, 1) lstm_scan_e(
    const float* __restrict__ xg, const float4* __restrict__ wtp,
    float* __restrict__ xf2, float* __restrict__ xb2)
{
    int blk = blockIdx.x;
    int dir = blk >> 6;            // 0..1
    int bp  = blk & 63;            // b-pair index
    int h   = threadIdx.x;         // hidden unit 0..255

    const float4* wt = wtp + ((size_t)dir << 16);   // [gate][k4][hid]
    float* xo = dir ? xb2 : xf2;

    __shared__ float hsA[HID_ * 2];   // [hid][bsub] double buffer
    __shared__ float hsB[HID_ * 2];

    hsA[h * 2] = 0.f; hsA[h * 2 + 1] = 0.f;
    float c0 = 0.f, c1 = 0.f;
    __syncthreads();

    for (int t = 0; t < L_; ++t) {
        int slot = dir ? (L_ - 1 - t) : t;
        const float* hs = (t & 1) ? hsB : hsA;
        float*       hw = (t & 1) ? hsA : hsB;

        // xg gate preloads (consumed in epilogue -> latency hidden by k-loop)
        const float* xbase = xg + (((size_t)dir * L_ + slot) * 64 + bp) * 2048;
        float2 gI = *(const float2*)(xbase + (0 * 256 + h) * 2);
        float2 gF = *(const float2*)(xbase + (1 * 256 + h) * 2);
        float2 gG = *(const float2*)(xbase + (2 * 256 + h) * 2);
        float2 gO = *(const float2*)(xbase + (3 * 256 + h) * 2);

        float aI0 = 0.f, aI1 = 0.f, aF0 = 0.f, aF1 = 0.f;
        float aG0 = 0.f, aG1 = 0.f, aO0 = 0.f, aO1 = 0.f;
        const float4* hp = (const float4*)hs;   // hp[q] = 2 hid x 2 b
        #pragma unroll 8
        for (int k4 = 0; k4 < HID_ / 4; ++k4) {
            float4 wI = wt[0 * 16384 + k4 * 256 + h];   // coalesced 1KB/wave
            float4 wF = wt[1 * 16384 + k4 * 256 + h];
            float4 wG = wt[2 * 16384 + k4 * 256 + h];
            float4 wO = wt[3 * 16384 + k4 * 256 + h];
            float4 h0 = hp[k4 * 2];                     // k=4k4+0,1 x 2b
            float4 h1 = hp[k4 * 2 + 1];                 // k=4k4+2,3 x 2b
            aI0 = fmaf(wI.x, h0.x, aI0); aI1 = fmaf(wI.x, h0.y, aI1);
            aF0 = fmaf(wF.x, h0.x, aF0); aF1 = fmaf(wF.x, h0.y, aF1);
            aG0 = fmaf(wG.x, h0.x, aG0); aG1 = fmaf(wG.x, h0.y, aG1);
            aO0 = fmaf(wO.x, h0.x, aO0); aO1 = fmaf(wO.x, h0.y, aO1);
            aI0 = fmaf(wI.y, h0.z, aI0); aI1 = fmaf(wI.y, h0.w, aI1);
            aF0 = fmaf(wF.y, h0.z, aF0); aF1 = fmaf(wF.y, h0.w, aF1);
            aG0 = fmaf(wG.y, h0.z, aG0); aG1 = fmaf(wG.y, h0.w, aG1);
            aO0 = fmaf(wO.y, h0.z, aO0); aO1 = fmaf(wO.y, h0.w, aO1);
            aI0 = fmaf(wI.z, h1.x, aI0); aI1 = fmaf(wI.z, h1.y, aI1);
            aF0 = fmaf(wF.z, h1.x, aF0); aF1 = fmaf(wF.z, h1.y, aF1);
            aG0 = fmaf(wG.z, h1.x, aG0); aG1 = fmaf(wG.z, h1.y, aG1);
            aO0 = fmaf(wO.z, h1.x, aO0); aO1 = fmaf(wO.z, h1.y, aO1);
            aI0 = fmaf(wI.w, h1.z, aI0); aI1 = fmaf(wI.w, h1.w, aI1);
            aF0 = fmaf(wF.w, h1.z, aF0); aF1 = fmaf(wF.w, h1.w, aF1);
            aG0 = fmaf(wG.w, h1.z, aG0); aG1 = fmaf(wG.w, h1.w, aG1);
            aO0 = fmaf(wO.w, h1.z, aO0); aO1 = fmaf(wO.w, h1.w, aO1);
        }

        // thread-local gate coupling (no LDS exchange needed)
        float i0 = 1.f / (1.f + expf(-(aI0 + gI.x)));
        float f0 = 1.f / (1.f + expf(-(aF0 + gF.x)));
        float g0 = tanhf(aG0 + gG.x);
        float o0 = 1.f / (1.f + expf(-(aO0 + gO.x)));
        c0 = f0 * c0 + i0 * g0;
        float hv0 = o0 * tanhf(c0);

        float i1 = 1.f / (1.f + expf(-(aI1 + gI.y)));
        float f1 = 1.f / (1.f + expf(-(aF1 + gF.y)));
        float g1 = tanhf(aG1 + gG.y);
        float o1 = 1.f / (1.f + expf(-(aO1 + gO.y)));
        c1 = f1 * c1 + i1 * g1;
        float hv1 = o1 * tanhf(c1);

        hw[h * 2] = hv0; hw[h * 2 + 1] = hv1;
        // block-friendly output layout [slot][bp][hid*2+bs] -> coalesced 8B/lane
        float* xp = xo + ((size_t)slot * 64 + bp) * 512 + h * 2;
        xp[0] = hv0; xp[1] = hv1;
        __syncthreads();   // hw visible before next step's reads
    }
}

// remap [slot][bp][hid*2+bs] -> x[slot][hid][b], summing directions
__global__ void x_add(const float* __restrict__ xf2, const float* __restrict__ xb2,
                      float* __restrict__ x)
{
    int idx = blockIdx.x * 256 + threadIdx.x;   // exactly L_*64*512 threads
    float v = xf2[idx] + xb2[idx];
    int slot = idx >> 15;          // / 32768
    int rem  = idx & 32767;
    int bp = rem >> 9;
    int q  = rem & 511;
    int j  = q >> 1, bs = q & 1;
    x[((size_t)slot * HID_ + j) * B_ + bp * 2 + bs] = v;
}

// ---------------------------------------------------------------------------
// Phase 3: entity features, attention, primary capsules
// ---------------------------------------------------------------------------
__global__ void find_entity(const int* __restrict__ pos1, const int* __restrict__ pos2,
                            int* __restrict__ e)
{
    int b = threadIdx.x;
    int e1 = 0, e2 = 0;
    for (int l = L_ - 1; l >= 0; --l) if (pos1[b * L_ + l] == ENTITY) e1 = l;
    for (int l = L_ - 1; l >= 0; --l) if (pos2[b * L_ + l] == ENTITY) e2 = l;
    e[b] = e1; e[B_ + b] = e2;
}

__global__ void compute_he(const float* __restrict__ x, const int* __restrict__ e,
                           float* __restrict__ he)
{
    int j = blockIdx.x, b = threadIdx.x;
    int e1 = e[b], e2 = e[B_ + b];
    he[j * B_ + b] = x[((size_t)e1 * HID_ + j) * B_ + b] + x[((size_t)e2 * HID_ + j) * B_ + b];
}

__global__ void att_logits(const float* __restrict__ x, const float* __restrict__ he,
                           float* __restrict__ logits)
{
    int l = blockIdx.x, b = threadIdx.x;
    float acc = 0.f;
    for (int j = 0; j < HID_; ++j)
        acc = fmaf(x[((size_t)l * HID_ + j) * B_ + b], he[j * B_ + b], acc);
    logits[l * B_ + b] = acc;
}

__global__ void att_softmax(const float* __restrict__ logits, float* __restrict__ att)
{
    int b = threadIdx.x;
    float m = -1e30f;
    for (int l = 0; l < L_; ++l) m = fmaxf(m, logits[l * B_ + b]);
    float s = 0.f;
    for (int l = 0; l < L_; ++l) s += expf(logits[l * B_ + b] - m);
    float inv = 1.f / s;
    for (int l = 0; l < L_; ++l) att[l * B_ + b] = expf(logits[l * B_ + b] - m) * inv;
}

// primary capsules: u[i][b][c], squashed
__global__ void u_squash(const float* __restrict__ x, float* __restrict__ u)
{
    int i = blockIdx.x, b = threadIdx.x;
    int l = i >> 4, cap = i & 15;
    float vals[16]; float n2 = 0.f;
    #pragma unroll
    for (int c2 = 0; c2 < 16; ++c2) {
        float v = x[((size_t)l * HID_ + cap * 16 + c2) * B_ + b];
        vals[c2] = v; n2 = fmaf(v, v, n2);
    }
    float f = (n2 / (1.f + n2)) / sqrtf(n2 + 1e-9f);
    #pragma unroll
    for (int c2 = 0; c2 < 16; ++c2)
        u[((size_t)i * B_ + b) * 16 + c2] = vals[c2] * f;
}

// ---------------------------------------------------------------------------
// Phase 4: routing
// ---------------------------------------------------------------------------
__global__ void bb_init(const float* __restrict__ br, float* __restrict__ bb)
{
    int idx = blockIdx.x * 256 + threadIdx.x;   // exactly B_*NI*NCLASS threads
    bb[idx] = br[idx % (NI * NCLASS)];
}

__global__ void __launch_bounds__(320) s_pass(
    const float* __restrict__ u, const float* __restrict__ W,
    const float* __restrict__ bb, const float* __restrict__ att,
    float* __restrict__ partial)
{
    int ic = blockIdx.x, bt = blockIdx.y;
    int i0 = ic * 16, b0 = bt * 16;
    __shared__ float C[16][16][20];   // [bl][il][o], padded
    int tid = threadIdx.x;
    if (tid < 256) {
        int bl = tid >> 4, il = tid & 15;
        int b = b0 + bl, i = i0 + il;
        const float* bbp = bb + ((size_t)b * NI + i) * NCLASS;
        float m = bbp[0];
        #pragma unroll
        for (int o = 1; o < NCLASS; ++o) m = fmaxf(m, bbp[o]);
        float s = 0.f; float e[NCLASS];
        #pragma unroll
        for (int o = 0; o < NCLASS; ++o) { e[o] = expf(bbp[o] - m); s += e[o]; }
        float al = att[(i >> 4) * B_ + b] / s;
        #pragma unroll
        for (int o = 0; o < NCLASS; ++o) C[bl][il][o] = e[o] * al;
    }
    __syncthreads();
    if (tid >= OD) return;
    int od = tid, o = od >> 4;
    float acc[16];
    #pragma unroll
    for (int bl = 0; bl < 16; ++bl) acc[bl] = 0.f;
    for (int il = 0; il < 16; ++il) {
        int i = i0 + il;
        const float* wp = W + (size_t)i * 16 * OD + od;
        float w[16];
        #pragma unroll
        for (int c2 = 0; c2 < 16; ++c2) w[c2] = wp[c2 * OD];     // coalesced over od
        const float* up = u + ((size_t)i * B_ + b0) * 16;        // uniform -> s_load
        #pragma unroll
        for (int bl = 0; bl < 16; ++bl) {
            float uh = 0.f;
            #pragma unroll
            for (int c2 = 0; c2 < 16; ++c2) uh = fmaf(up[bl * 16 + c2], w[c2], uh);
            acc[bl] = fmaf(C[bl][il][o], uh, acc[bl]);
        }
    }
    #pragma unroll
    for (int bl = 0; bl < 16; ++bl)
        partial[((size_t)ic * B_ + b0 + bl) * OD + od] = acc[bl];
}

__global__ void s_reduce(const float* __restrict__ partial, float* __restrict__ s)
{
    int idx = blockIdx.x * 256 + threadIdx.x;   // exactly B_*OD threads
    int b = idx / OD, od = idx - b * OD;
    float acc = 0.f;
    for (int ic = 0; ic < 100; ++ic) acc += partial[((size_t)ic * B_ + b) * OD + od];
    s[idx] = acc;
}

__global__ void squash_v(const float* __restrict__ s, float* __restrict__ v,
                         float* __restrict__ out, int write_out)
{
    int idx = blockIdx.x * 256 + threadIdx.x;
    if (idx >= B_ * NCLASS) return;
    const float* sp = s + (size_t)idx * 16;     // b*304 + o*16 == idx*16
    float vals[16]; float n2 = 0.f;
    #pragma unroll
    for (int d = 0; d < 16; ++d) { vals[d] = sp[d]; n2 = fmaf(vals[d], vals[d], n2); }
    float f = (n2 / (1.f + n2)) / sqrtf(n2 + 1e-9f);
    float n2v = 0.f;
    #pragma unroll
    for (int d = 0; d < 16; ++d) {
        float vv = vals[d] * f;
        v[(size_t)idx * 16 + d] = vv;
        n2v = fmaf(vv, vv, n2v);
    }
    if (write_out) out[idx] = sqrtf(n2v + 1e-9f);
}

__global__ void __launch_bounds__(320) bb_pass(
    const float* __restrict__ u, const float* __restrict__ W,
    const float* __restrict__ v, float* __restrict__ bb)
{
    int ic = blockIdx.x, bt = blockIdx.y;
    int i0 = ic * 16, b0 = bt * 16;
    int tid = threadIdx.x;
    if (tid >= OD) return;
    int od = tid, o = od >> 4, d = od & 15;
    float vv[16];
    #pragma unroll
    for (int bl = 0; bl < 16; ++bl) vv[bl] = v[(size_t)(b0 + bl) * OD + od];
    for (int il = 0; il < 16; ++il) {
        int i = i0 + il;
        const float* wp = W + (size_t)i * 16 * OD + od;
        float w[16];
        #pragma unroll
        for (int c2 = 0; c2 < 16; ++c2) w[c2] = wp[c2 * OD];
        const float* up = u + ((size_t)i * B_ + b0) * 16;
        #pragma unroll
        for (int bl = 0; bl < 16; ++bl) {
            float uh = 0.f;
            #pragma unroll
            for (int c2 = 0; c2 < 16; ++c2) uh = fmaf(up[bl * 16 + c2], w[c2], uh);
            float p = uh * vv[bl];
            p += __shfl_xor(p, 1);
            p += __shfl_xor(p, 2);
            p += __shfl_xor(p, 4);
            p += __shfl_xor(p, 8);
            if (d == 0) bb[((size_t)(b0 + bl) * NI + i) * NCLASS + o] += p;
        }
    }
}

// ---------------------------------------------------------------------------
extern "C" void kernel_launch(void* const* d_in, const int* in_sizes, int n_in,
                              void* d_out, int out_size, void* d_ws, size_t ws_size,
                              hipStream_t stream)
{
    (void)in_sizes; (void)n_in; (void)out_size; (void)ws_size;
    const int*   word = (const int*)d_in[0];
    const int*   tag  = (const int*)d_in[1];
    const int*   pos1 = (const int*)d_in[2];
    const int*   pos2 = (const int*)d_in[3];
    const float* we   = (const float*)d_in[4];
    const float* te   = (const float*)d_in[5];
    const float* p1e  = (const float*)d_in[6];
    const float* p2e  = (const float*)d_in[7];
    const float* wihf = (const float*)d_in[8];
    const float* whhf = (const float*)d_in[9];
    const float* bihf = (const float*)d_in[10];
    const float* bhhf = (const float*)d_in[11];
    const float* wihb = (const float*)d_in[12];
    const float* whhb = (const float*)d_in[13];
    const float* bihb = (const float*)d_in[14];
    const float* bhhb = (const float*)d_in[15];
    const float* Wc   = (const float*)d_in[16];
    const float* br   = (const float*)d_in[17];

    float* wsp    = (float*)d_ws;
    float* emb    = wsp;                       //  2,048,000
    float* xg     = wsp + 2048000;             // 26,214,400
    float* xf     = xg + 26214400;             //  3,276,800
    float* xb     = xf + 3276800;              //  3,276,800
    float* he     = xb + 3276800;              //     32,768
    float* logits = he + 32768;                //     12,800
    float* att    = logits + 12800;            //     12,800
    int*   e      = (int*)(att + 12800);       //        256 ints
    // packed recurrent weights alias the (dead-after-gemm_xg) emb region
    float4* wtp = (float4*)emb;                //  524,288 floats (2 MB)
    // post-scan buffers alias the (dead-after-scan) xg region
    float* x    = xg;                          //  3,276,800
    float* u    = xg + 3276800;                //  3,276,800
    float* bb   = xg + 6553600;                //  3,891,200
    float* part = xg + 10444800;               //  3,891,200
    float* s    = xg + 14336000;               //     38,912
    float* v    = s + 38912;                   //     38,912
    float* out  = (float*)d_out;

    emb_gather<<<8000, 256, 0, stream>>>(word, tag, pos1, pos2, we, te, p1e, p2e, emb);
    gemm_xg<<<dim3(8, 100, 2), 256, 0, stream>>>(emb, wihf, bihf, bhhf, wihb, bihb, bhhb, xg);
    whh_pack<<<512, 256, 0, stream>>>(whhf, whhb, wtp);
    lstm_scan_e<<<128, 256, 0, stream>>>(xg, wtp, xf, xb);
    x_add<<<12800, 256, 0, stream>>>(xf, xb, x);
    find_entity<<<1, 128, 0, stream>>>(pos1, pos2, e);
    compute_he<<<256, 128, 0, stream>>>(x, e, he);
    att_logits<<<100, 128, 0, stream>>>(x, he, logits);
    att_softmax<<<1, 128, 0, stream>>>(logits, att);
    u_squash<<<1600, 128, 0, stream>>>(x, u);
    bb_init<<<15200, 256, 0, stream>>>(br, bb);
    for (int it = 0; it < 3; ++it) {
        s_pass<<<dim3(100, 8), 320, 0, stream>>>(u, Wc, bb, att, part);
        s_reduce<<<152, 256, 0, stream>>>(part, s);
        squash_v<<<10, 256, 0, stream>>>(s, v, out, (it == 2) ? 1 : 0);
        if (it < 2) bb_pass<<<dim3(100, 8), 320, 0, stream>>>(u, Wc, v, bb);
    }
}

// Round 4
// 1495.784 us; speedup vs baseline: 1.2530x; 1.2530x over previous
//
#include <hip/hip_runtime.h>
#include <math.h>

#define B_     128
#define L_     100
#define HID_   256
#define IND_   160
#define NCLASS 19
#define CAPD   16
#define NI     1600      // L_ * NUM_CAPS
#define OD     304       // NCLASS * CAPD
#define ENTITY 68

typedef _Float16 half2_t __attribute__((ext_vector_type(2)));

__device__ inline half2_t as_h2(unsigned u) {
    union { unsigned u; half2_t h; } x; x.u = u; return x.h;
}
__device__ inline unsigned pack2(float a, float b) {
    union { unsigned u; half2_t h; } x;
    x.h = (half2_t){ (_Float16)a, (_Float16)b };   // RTN converts
    return x.u;
}
__device__ inline float fdot2_(unsigned w, unsigned h, float acc) {
#if __has_builtin(__builtin_amdgcn_fdot2)
    return __builtin_amdgcn_fdot2(as_h2(w), as_h2(h), acc, false);
#else
    half2_t wh = as_h2(w), hh = as_h2(h);
    acc = fmaf((float)wh.x, (float)hh.x, acc);
    return fmaf((float)wh.y, (float)hh.y, acc);
#endif
}

// ---------------------------------------------------------------------------
// Phase 0: embedding gather -> emb [b*L_+t][160]
// ---------------------------------------------------------------------------
__global__ void emb_gather(const int* __restrict__ word, const int* __restrict__ tag,
                           const int* __restrict__ pos1, const int* __restrict__ pos2,
                           const float* __restrict__ we, const float* __restrict__ te,
                           const float* __restrict__ p1e, const float* __restrict__ p2e,
                           float* __restrict__ emb)
{
    int idx = blockIdx.x * 256 + threadIdx.x;          // exactly B_*L_*IND_ threads
    int bt = idx / IND_;
    int k  = idx - bt * IND_;
    float v;
    if (k < 100)      v = we[word[bt] * 100 + k];
    else if (k < 120) v = te[tag[bt] * 20 + (k - 100)];
    else if (k < 140) v = p1e[pos1[bt] * 20 + (k - 120)];
    else              v = p2e[pos2[bt] * 20 + (k - 140)];
    emb[idx] = v;
}

// ---------------------------------------------------------------------------
// Phase 1: input-gate GEMM.
// xg layout: [dir][t][bpair(64)][gj(1024)][2]  (b = bpair*2 + c)
// so the scan's per-step gate load is a coalesced dwordx2 over lanes=hid.
// ---------------------------------------------------------------------------
__global__ void __launch_bounds__(256) gemm_xg(
    const float* __restrict__ emb,
    const float* __restrict__ wihf, const float* __restrict__ bihf, const float* __restrict__ bhhf,
    const float* __restrict__ wihb, const float* __restrict__ bihb, const float* __restrict__ bhhb,
    float* __restrict__ xg)
{
    int gt  = blockIdx.x;
    int t   = blockIdx.y;
    int dir = blockIdx.z;
    const float* w  = dir ? wihb : wihf;
    const float* bi = dir ? bihb : bihf;
    const float* bh = dir ? bhhb : bhhf;
    int gj0 = gt * 128;

    __shared__ float wsh[32][132];   // [k][gj], padded
    __shared__ float esh[32][132];   // [k][b],  padded

    int tid = threadIdx.x;
    int tx = tid & 15, ty = tid >> 4;

    float acc[8][8];
    #pragma unroll
    for (int i = 0; i < 8; ++i)
        #pragma unroll
        for (int j = 0; j < 8; ++j) acc[i][j] = 0.f;

    for (int k0 = 0; k0 < IND_; k0 += 32) {
        __syncthreads();
        #pragma unroll
        for (int m = 0; m < 16; ++m) {
            int e = m * 256 + tid;        // 0..4095
            int k = e & 31, g = e >> 5;   // g: row (gj or b)
            wsh[k][g] = w[(gj0 + g) * IND_ + k0 + k];
            esh[k][g] = emb[(g * L_ + t) * IND_ + k0 + k];
        }
        __syncthreads();
        #pragma unroll
        for (int k = 0; k < 32; ++k) {
            float wv[8], ev[8];
            #pragma unroll
            for (int q = 0; q < 8; ++q) wv[q] = wsh[k][ty * 8 + q];
            #pragma unroll
            for (int q = 0; q < 8; ++q) ev[q] = esh[k][tx * 8 + q];
            #pragma unroll
            for (int i = 0; i < 8; ++i)
                #pragma unroll
                for (int j = 0; j < 8; ++j) acc[i][j] = fmaf(wv[i], ev[j], acc[i][j]);
        }
    }
    #pragma unroll
    for (int i = 0; i < 8; ++i) {
        int gj = gj0 + ty * 8 + i;
        float bias = bi[gj] + bh[gj];
        #pragma unroll
        for (int j = 0; j < 8; ++j) {
            int b = tx * 8 + j;
            xg[((((size_t)dir * L_ + t) * 64 + (b >> 1)) * 1024 + gj) * 2 + (b & 1)]
                = acc[i][j] + bias;
        }
    }
}

// ---------------------------------------------------------------------------
// Phase 1.5: pack recurrent weights to f16x2.
// wp16[dir][p(128)][hid(256)][gate(4)] : uint = {f16(w[g][hid][2p]), f16(w[g][hid][2p+1])}
// Scan loads a uint4 (all 4 gates for one (p,hid)) per lane: lanes = consecutive
// hid -> fully coalesced 16B/lane, and HALF the bytes of the fp32 stream that
// was the measured per-CU BW limit (~110 GB/s/CU, R2/R3 both at 9.3us/step).
// ---------------------------------------------------------------------------
__global__ void whh_pack16(const float* __restrict__ whhf, const float* __restrict__ whhb,
                           unsigned* __restrict__ wp)
{
    int gid = blockIdx.x * 256 + threadIdx.x;   // exactly 2*128*256*4 threads
    int g   = gid & 3;
    int h   = (gid >> 2) & 255;
    int p   = (gid >> 10) & 127;
    int dir = gid >> 17;
    const float* whh = dir ? whhb : whhf;
    const float* row = whh + (size_t)(g * 256 + h) * HID_;
    wp[gid] = pack2(row[2 * p], row[2 * p + 1]);
}

// ---------------------------------------------------------------------------
// Phase 2: BiLSTM scan. Block = (dir, b-pair): 128 blocks x 256 threads.
// Thread = one hidden unit, all 4 gates, 2 batch columns. f16 weights via
// v_dot2_f32_f16 (fp32 accumulate): per step/CU VMEM 512KB (was 1MB, the
// binding pipe), VALU 1024 dot2 (was 2048 fma), LDS 128 broadcast b64.
// h packed to f16x2 per step via shfl_xor(1) + pack. xg stays exact fp32.
// ---------------------------------------------------------------------------
__global__ void __launch_bounds__(256, 1) lstm_scan_h(
    const float* __restrict__ xg, const uint4* __restrict__ wp16,
    float* __restrict__ xf2, float* __restrict__ xb2)
{
    int blk = blockIdx.x;
    int dir = blk >> 6;            // 0..1
    int bp  = blk & 63;            // b-pair index
    int h   = threadIdx.x;         // hidden unit 0..255

    const uint4* wt = wp16 + (size_t)dir * 128 * 256;   // [p][hid] uint4
    float* xo = dir ? xb2 : xf2;

    __shared__ uint2 hA[128];   // [p] = {bs0: f16x2(h[2p],h[2p+1]), bs1: same}
    __shared__ uint2 hB[128];

    ((unsigned*)hA)[h] = 0u;    // h=0 -> f16 0x0000 pairs
    float c0 = 0.f, c1 = 0.f;
    __syncthreads();

    for (int t = 0; t < L_; ++t) {
        int slot = dir ? (L_ - 1 - t) : t;
        const uint2* hp = (t & 1) ? hB : hA;
        unsigned*    hw = (unsigned*)((t & 1) ? hA : hB);

        // xg gate preloads (fp32, exact; consumed in epilogue)
        const float* xbase = xg + (((size_t)dir * L_ + slot) * 64 + bp) * 2048;
        float2 gI = *(const float2*)(xbase + (0 * 256 + h) * 2);
        float2 gF = *(const float2*)(xbase + (1 * 256 + h) * 2);
        float2 gG = *(const float2*)(xbase + (2 * 256 + h) * 2);
        float2 gO = *(const float2*)(xbase + (3 * 256 + h) * 2);

        float aI0 = 0.f, aI1 = 0.f, aF0 = 0.f, aF1 = 0.f;
        float aG0 = 0.f, aG1 = 0.f, aO0 = 0.f, aO1 = 0.f;
        #pragma unroll 16
        for (int p = 0; p < 128; ++p) {
            uint4 w4 = wt[p * 256 + h];   // coalesced 16B/lane, 4 gates x k-pair
            uint2 hb = hp[p];             // broadcast (uniform addr per wave)
            aI0 = fdot2_(w4.x, hb.x, aI0); aI1 = fdot2_(w4.x, hb.y, aI1);
            aF0 = fdot2_(w4.y, hb.x, aF0); aF1 = fdot2_(w4.y, hb.y, aF1);
            aG0 = fdot2_(w4.z, hb.x, aG0); aG1 = fdot2_(w4.z, hb.y, aG1);
            aO0 = fdot2_(w4.w, hb.x, aO0); aO1 = fdot2_(w4.w, hb.y, aO1);
        }

        // thread-local gate coupling (fp32 exact on the xg side)
        float i0 = 1.f / (1.f + expf(-(aI0 + gI.x)));
        float f0 = 1.f / (1.f + expf(-(aF0 + gF.x)));
        float g0 = tanhf(aG0 + gG.x);
        float o0 = 1.f / (1.f + expf(-(aO0 + gO.x)));
        c0 = f0 * c0 + i0 * g0;
        float hv0 = o0 * tanhf(c0);

        float i1 = 1.f / (1.f + expf(-(aI1 + gI.y)));
        float f1 = 1.f / (1.f + expf(-(aF1 + gF.y)));
        float g1 = tanhf(aG1 + gG.y);
        float o1 = 1.f / (1.f + expf(-(aO1 + gO.y)));
        c1 = f1 * c1 + i1 * g1;
        float hv1 = o1 * tanhf(c1);

        // pack h to f16x2 pairs: thread 2p and 2p+1 exchange via shfl_xor(1)
        float n0 = __shfl_xor(hv0, 1);
        float n1 = __shfl_xor(hv1, 1);
        hw[h] = (h & 1) ? pack2(n1, hv1)    // odd h -> slot [p][bs1]: lo=h[2p],hi=h[2p+1]
                        : pack2(hv0, n0);   // even h -> slot [p][bs0]
        // f32 output, block-friendly layout [slot][bp][hid*2+bs]
        float* xp = xo + ((size_t)slot * 64 + bp) * 512 + h * 2;
        xp[0] = hv0; xp[1] = hv1;
        __syncthreads();   // hw visible before next step's reads
    }
}

// remap [slot][bp][hid*2+bs] -> x[slot][hid][b], summing directions
__global__ void x_add(const float* __restrict__ xf2, const float* __restrict__ xb2,
                      float* __restrict__ x)
{
    int idx = blockIdx.x * 256 + threadIdx.x;   // exactly L_*64*512 threads
    float v = xf2[idx] + xb2[idx];
    int slot = idx >> 15;          // / 32768
    int rem  = idx & 32767;
    int bp = rem >> 9;
    int q  = rem & 511;
    int j  = q >> 1, bs = q & 1;
    x[((size_t)slot * HID_ + j) * B_ + bp * 2 + bs] = v;
}

// ---------------------------------------------------------------------------
// Phase 3: entity features, attention, primary capsules
// ---------------------------------------------------------------------------
__global__ void find_entity(const int* __restrict__ pos1, const int* __restrict__ pos2,
                            int* __restrict__ e)
{
    int b = threadIdx.x;
    int e1 = 0, e2 = 0;
    for (int l = L_ - 1; l >= 0; --l) if (pos1[b * L_ + l] == ENTITY) e1 = l;
    for (int l = L_ - 1; l >= 0; --l) if (pos2[b * L_ + l] == ENTITY) e2 = l;
    e[b] = e1; e[B_ + b] = e2;
}

__global__ void compute_he(const float* __restrict__ x, const int* __restrict__ e,
                           float* __restrict__ he)
{
    int j = blockIdx.x, b = threadIdx.x;
    int e1 = e[b], e2 = e[B_ + b];
    he[j * B_ + b] = x[((size_t)e1 * HID_ + j) * B_ + b] + x[((size_t)e2 * HID_ + j) * B_ + b];
}

__global__ void att_logits(const float* __restrict__ x, const float* __restrict__ he,
                           float* __restrict__ logits)
{
    int l = blockIdx.x, b = threadIdx.x;
    float acc = 0.f;
    for (int j = 0; j < HID_; ++j)
        acc = fmaf(x[((size_t)l * HID_ + j) * B_ + b], he[j * B_ + b], acc);
    logits[l * B_ + b] = acc;
}

__global__ void att_softmax(const float* __restrict__ logits, float* __restrict__ att)
{
    int b = threadIdx.x;
    float m = -1e30f;
    for (int l = 0; l < L_; ++l) m = fmaxf(m, logits[l * B_ + b]);
    float s = 0.f;
    for (int l = 0; l < L_; ++l) s += expf(logits[l * B_ + b] - m);
    float inv = 1.f / s;
    for (int l = 0; l < L_; ++l) att[l * B_ + b] = expf(logits[l * B_ + b] - m) * inv;
}

// primary capsules: u[i][b][c], squashed
__global__ void u_squash(const float* __restrict__ x, float* __restrict__ u)
{
    int i = blockIdx.x, b = threadIdx.x;
    int l = i >> 4, cap = i & 15;
    float vals[16]; float n2 = 0.f;
    #pragma unroll
    for (int c2 = 0; c2 < 16; ++c2) {
        float v = x[((size_t)l * HID_ + cap * 16 + c2) * B_ + b];
        vals[c2] = v; n2 = fmaf(v, v, n2);
    }
    float f = (n2 / (1.f + n2)) / sqrtf(n2 + 1e-9f);
    #pragma unroll
    for (int c2 = 0; c2 < 16; ++c2)
        u[((size_t)i * B_ + b) * 16 + c2] = vals[c2] * f;
}

// ---------------------------------------------------------------------------
// Phase 4: routing
// ---------------------------------------------------------------------------
__global__ void bb_init(const float* __restrict__ br, float* __restrict__ bb)
{
    int idx = blockIdx.x * 256 + threadIdx.x;   // exactly B_*NI*NCLASS threads
    bb[idx] = br[idx % (NI * NCLASS)];
}

__global__ void __launch_bounds__(320) s_pass(
    const float* __restrict__ u, const float* __restrict__ W,
    const float* __restrict__ bb, const float* __restrict__ att,
    float* __restrict__ partial)
{
    int ic = blockIdx.x, bt = blockIdx.y;
    int i0 = ic * 16, b0 = bt * 16;
    __shared__ float C[16][16][20];   // [bl][il][o], padded
    int tid = threadIdx.x;
    if (tid < 256) {
        int bl = tid >> 4, il = tid & 15;
        int b = b0 + bl, i = i0 + il;
        const float* bbp = bb + ((size_t)b * NI + i) * NCLASS;
        float m = bbp[0];
        #pragma unroll
        for (int o = 1; o < NCLASS; ++o) m = fmaxf(m, bbp[o]);
        float s = 0.f; float e[NCLASS];
        #pragma unroll
        for (int o = 0; o < NCLASS; ++o) { e[o] = expf(bbp[o] - m); s += e[o]; }
        float al = att[(i >> 4) * B_ + b] / s;
        #pragma unroll
        for (int o = 0; o < NCLASS; ++o) C[bl][il][o] = e[o] * al;
    }
    __syncthreads();
    if (tid >= OD) return;
    int od = tid, o = od >> 4;
    float acc[16];
    #pragma unroll
    for (int bl = 0; bl < 16; ++bl) acc[bl] = 0.f;
    for (int il = 0; il < 16; ++il) {
        int i = i0 + il;
        const float* wp = W + (size_t)i * 16 * OD + od;
        float w[16];
        #pragma unroll
        for (int c2 = 0; c2 < 16; ++c2) w[c2] = wp[c2 * OD];     // coalesced over od
        const float* up = u + ((size_t)i * B_ + b0) * 16;        // uniform -> s_load
        #pragma unroll
        for (int bl = 0; bl < 16; ++bl) {
            float uh = 0.f;
            #pragma unroll
            for (int c2 = 0; c2 < 16; ++c2) uh = fmaf(up[bl * 16 + c2], w[c2], uh);
            acc[bl] = fmaf(C[bl][il][o], uh, acc[bl]);
        }
    }
    #pragma unroll
    for (int bl = 0; bl < 16; ++bl)
        partial[((size_t)ic * B_ + b0 + bl) * OD + od] = acc[bl];
}

__global__ void s_reduce(const float* __restrict__ partial, float* __restrict__ s)
{
    int idx = blockIdx.x * 256 + threadIdx.x;   // exactly B_*OD threads
    int b = idx / OD, od = idx - b * OD;
    float acc = 0.f;
    for (int ic = 0; ic < 100; ++ic) acc += partial[((size_t)ic * B_ + b) * OD + od];
    s[idx] = acc;
}

__global__ void squash_v(const float* __restrict__ s, float* __restrict__ v,
                         float* __restrict__ out, int write_out)
{
    int idx = blockIdx.x * 256 + threadIdx.x;
    if (idx >= B_ * NCLASS) return;
    const float* sp = s + (size_t)idx * 16;     // b*304 + o*16 == idx*16
    float vals[16]; float n2 = 0.f;
    #pragma unroll
    for (int d = 0; d < 16; ++d) { vals[d] = sp[d]; n2 = fmaf(vals[d], vals[d], n2); }
    float f = (n2 / (1.f + n2)) / sqrtf(n2 + 1e-9f);
    float n2v = 0.f;
    #pragma unroll
    for (int d = 0; d < 16; ++d) {
        float vv = vals[d] * f;
        v[(size_t)idx * 16 + d] = vv;
        n2v = fmaf(vv, vv, n2v);
    }
    if (write_out) out[idx] = sqrtf(n2v + 1e-9f);
}

__global__ void __launch_bounds__(320) bb_pass(
    const float* __restrict__ u, const float* __restrict__ W,
    const float* __restrict__ v, float* __restrict__ bb)
{
    int ic = blockIdx.x, bt = blockIdx.y;
    int i0 = ic * 16, b0 = bt * 16;
    int tid = threadIdx.x;
    if (tid >= OD) return;
    int od = tid, o = od >> 4, d = od & 15;
    float vv[16];
    #pragma unroll
    for (int bl = 0; bl < 16; ++bl) vv[bl] = v[(size_t)(b0 + bl) * OD + od];
    for (int il = 0; il < 16; ++il) {
        int i = i0 + il;
        const float* wp = W + (size_t)i * 16 * OD + od;
        float w[16];
        #pragma unroll
        for (int c2 = 0; c2 < 16; ++c2) w[c2] = wp[c2 * OD];
        const float* up = u + ((size_t)i * B_ + b0) * 16;
        #pragma unroll
        for (int bl = 0; bl < 16; ++bl) {
            float uh = 0.f;
            #pragma unroll
            for (int c2 = 0; c2 < 16; ++c2) uh = fmaf(up[bl * 16 + c2], w[c2], uh);
            float p = uh * vv[bl];
            p += __shfl_xor(p, 1);
            p += __shfl_xor(p, 2);
            p += __shfl_xor(p, 4);
            p += __shfl_xor(p, 8);
            if (d == 0) bb[((size_t)(b0 + bl) * NI + i) * NCLASS + o] += p;
        }
    }
}

// ---------------------------------------------------------------------------
extern "C" void kernel_launch(void* const* d_in, const int* in_sizes, int n_in,
                              void* d_out, int out_size, void* d_ws, size_t ws_size,
                              hipStream_t stream)
{
    (void)in_sizes; (void)n_in; (void)out_size; (void)ws_size;
    const int*   word = (const int*)d_in[0];
    const int*   tag  = (const int*)d_in[1];
    const int*   pos1 = (const int*)d_in[2];
    const int*   pos2 = (const int*)d_in[3];
    const float* we   = (const float*)d_in[4];
    const float* te   = (const float*)d_in[5];
    const float* p1e  = (const float*)d_in[6];
    const float* p2e  = (const float*)d_in[7];
    const float* wihf = (const float*)d_in[8];
    const float* whhf = (const float*)d_in[9];
    const float* bihf = (const float*)d_in[10];
    const float* bhhf = (const float*)d_in[11];
    const float* wihb = (const float*)d_in[12];
    const float* whhb = (const float*)d_in[13];
    const float* bihb = (const float*)d_in[14];
    const float* bhhb = (const float*)d_in[15];
    const float* Wc   = (const float*)d_in[16];
    const float* br   = (const float*)d_in[17];

    float* wsp    = (float*)d_ws;
    float* emb    = wsp;                       //  2,048,000
    float* xg     = wsp + 2048000;             // 26,214,400
    float* xf     = xg + 26214400;             //  3,276,800
    float* xb     = xf + 3276800;              //  3,276,800
    float* he     = xb + 3276800;              //     32,768
    float* logits = he + 32768;                //     12,800
    float* att    = logits + 12800;            //     12,800
    int*   e      = (int*)(att + 12800);       //        256 ints
    // packed f16 recurrent weights alias the (dead-after-gemm_xg) emb region
    unsigned* wp16 = (unsigned*)emb;           //  262,144 uints (1 MB)
    // post-scan buffers alias the (dead-after-scan) xg region
    float* x    = xg;                          //  3,276,800
    float* u    = xg + 3276800;                //  3,276,800
    float* bb   = xg + 6553600;                //  3,891,200
    float* part = xg + 10444800;               //  3,891,200
    float* s    = xg + 14336000;               //     38,912
    float* v    = s + 38912;                   //     38,912
    float* out  = (float*)d_out;

    emb_gather<<<8000, 256, 0, stream>>>(word, tag, pos1, pos2, we, te, p1e, p2e, emb);
    gemm_xg<<<dim3(8, 100, 2), 256, 0, stream>>>(emb, wihf, bihf, bhhf, wihb, bihb, bhhb, xg);
    whh_pack16<<<1024, 256, 0, stream>>>(whhf, whhb, wp16);
    lstm_scan_h<<<128, 256, 0, stream>>>(xg, (const uint4*)wp16, xf, xb);
    x_add<<<12800, 256, 0, stream>>>(xf, xb, x);
    find_entity<<<1, 128, 0, stream>>>(pos1, pos2, e);
    compute_he<<<256, 128, 0, stream>>>(x, e, he);
    att_logits<<<100, 128, 0, stream>>>(x, he, logits);
    att_softmax<<<1, 128, 0, stream>>>(logits, att);
    u_squash<<<1600, 128, 0, stream>>>(x, u);
    bb_init<<<15200, 256, 0, stream>>>(br, bb);
    for (int it = 0; it < 3; ++it) {
        s_pass<<<dim3(100, 8), 320, 0, stream>>>(u, Wc, bb, att, part);
        s_reduce<<<152, 256, 0, stream>>>(part, s);
        squash_v<<<10, 256, 0, stream>>>(s, v, out, (it == 2) ? 1 : 0);
        if (it < 2) bb_pass<<<dim3(100, 8), 320, 0, stream>>>(u, Wc, v, bb);
    }
}